// Round 3
// baseline (3537.714 us; speedup 1.0000x reference)
//
#include <hip/hip_runtime.h>
#include <hip/hip_bf16.h>

#define T_ 16384
#define H_ 2048
#define I_ 1024
#define E_ 8
#define K_ 2
#define R_ 16
#define P_ (T_*K_)   /* 32768 pairs */
#define BM 128
#define BK 32

typedef float  f32x4  __attribute__((ext_vector_type(4)));
typedef __bf16 bf16x4 __attribute__((ext_vector_type(4)));
typedef __bf16 bf16x8 __attribute__((ext_vector_type(8)));

// XOR swizzle: 8-element (16B) chunk index ^= (row>>1)&3  -> 2-way-free frag reads
__device__ __forceinline__ int swzc(int r, int c) {
  return (c & 7) | ((((c >> 3) ^ ((r >> 1) & 3)) & 3) << 3);
}

// fp32 -> (hi, lo) bf16 split; hi+lo captures ~16 mantissa bits (rel err ~2^-17)
__device__ __forceinline__ void cvt4(f32x4 v, bf16x4* h, bf16x4* l) {
#pragma unroll
  for (int j = 0; j < 4; ++j) {
    float f = v[j];
    __bf16 hh = (__bf16)f;
    (*h)[j] = hh;
    (*l)[j] = (__bf16)(f - (float)hh);
  }
}

__global__ __launch_bounds__(256) void zero_kernel(float* __restrict__ out, int* __restrict__ cnt) {
  size_t i = (size_t)blockIdx.x * 256 + threadIdx.x;
  f32x4 z = {0.f, 0.f, 0.f, 0.f};
  if (i < (size_t)T_ * H_ / 4) ((f32x4*)out)[i] = z;
  if (i < E_) cnt[i] = 0;
}

__global__ __launch_bounds__(256) void route_kernel(const int* __restrict__ ids,
                                                    const float* __restrict__ tw,
                                                    int* __restrict__ cnt,
                                                    int* __restrict__ tok,
                                                    float* __restrict__ wgt) {
  int s = blockIdx.x * 256 + threadIdx.x;
  if (s < P_) {
    int e = ids[s];
    int pos = atomicAdd(&cnt[e], 1);
    tok[e * P_ + pos] = s;
    wgt[e * P_ + pos] = tw[s];
  }
}

// U[s][r] = sum_h x[t][h] * a1[e][r][h]   (one wave per pair)
__global__ __launch_bounds__(256) void lora_u_kernel(const float* __restrict__ x,
                                                     const float* __restrict__ a1,
                                                     const int* __restrict__ ids,
                                                     float* __restrict__ U) {
  int sIdx = blockIdx.x * 4 + (threadIdx.x >> 6);
  int lane = threadIdx.x & 63;
  int t = sIdx >> 1;
  int e = ids[sIdx];
  int r = lane >> 2, part = lane & 3;
  const float* xp = x + (size_t)t * H_;
  const float* ap = a1 + ((size_t)e * R_ + r) * H_;
  float acc = 0.f;
  for (int h0 = part * 4; h0 < H_; h0 += 16) {
    f32x4 xv = *(const f32x4*)(xp + h0);
    f32x4 av = *(const f32x4*)(ap + h0);
    acc += xv[0]*av[0] + xv[1]*av[1] + xv[2]*av[2] + xv[3]*av[3];
  }
  acc += __shfl_xor(acc, 1);
  acc += __shfl_xor(acc, 2);
  if (part == 0) U[(size_t)sIdx * R_ + r] = acc;
}

// V[s][r] = sum_i act[s][i] * a2[e][r][i]
__global__ __launch_bounds__(256) void lora_v_kernel(const __bf16* __restrict__ acth,
                                                     const __bf16* __restrict__ actl,
                                                     const float* __restrict__ a2,
                                                     const int* __restrict__ ids,
                                                     float* __restrict__ V) {
  int sIdx = blockIdx.x * 4 + (threadIdx.x >> 6);
  int lane = threadIdx.x & 63;
  int e = ids[sIdx];
  int r = lane >> 2, part = lane & 3;
  const __bf16* hp = acth + (size_t)sIdx * I_;
  const __bf16* lp = actl + (size_t)sIdx * I_;
  const float* ap = a2 + ((size_t)e * R_ + r) * I_;
  float acc = 0.f;
  for (int i0 = part * 4; i0 < I_; i0 += 16) {
    bf16x4 hv = *(const bf16x4*)(hp + i0);
    bf16x4 lv = *(const bf16x4*)(lp + i0);
    f32x4 av = *(const f32x4*)(ap + i0);
#pragma unroll
    for (int j = 0; j < 4; ++j) acc += ((float)hv[j] + (float)lv[j]) * av[j];
  }
  acc += __shfl_xor(acc, 1);
  acc += __shfl_xor(acc, 2);
  if (part == 0) V[(size_t)sIdx * R_ + r] = acc;
}

// GEMM1: act[s, c] = silu(g)*u, g/u = x@w13^T (+ U@b1^T), split-bf16 3-pass MFMA.
// Block: 128 pair-rows x 64 act cols (gate+up dual accumulators).
__global__ __launch_bounds__(256, 2) void gemm1_kernel(
    const float* __restrict__ x, const float* __restrict__ w13,
    const float* __restrict__ b1, const float* __restrict__ U,
    const int* __restrict__ cnt, const int* __restrict__ tok,
    __bf16* __restrict__ acth, __bf16* __restrict__ actl) {
  const int e = blockIdx.z;
  const int n = cnt[e];
  const int row0 = blockIdx.x * BM;
  if (row0 >= n) return;
  const int c0 = blockIdx.y * 64;

  __shared__ __bf16 lAh[2][BM*BK], lAl[2][BM*BK], lBh[2][BM*BK], lBl[2][BM*BK];
  __shared__ float sU[BM * R_];
  __shared__ int sTok[BM];

  const int tS = threadIdx.x;
  const int lane = tS & 63, wid = tS >> 6;
  const int wm = (wid & 1) * 64, wn = (wid >> 1) * 32;
  const int lr = lane & 15, lk = lane >> 4;

  // staging: thread covers (srow + q*32, sc4..sc4+3), q=0..3, for both A and B tiles
  const int srow = tS >> 3;
  const int sc4 = (tS & 7) * 4;
  const float* aptr[4];
  const float* bptr[4];
#pragma unroll
  for (int q = 0; q < 4; ++q) {
    int r = srow + q * 32;
    int i = row0 + r; if (i >= n) i = n - 1;
    int s = tok[e * P_ + i];
    aptr[q] = x + (size_t)(s >> 1) * H_ + sc4;
    int bn = (r < 64) ? (c0 + r) : (I_ + c0 + (r - 64));
    bptr[q] = w13 + ((size_t)e * (2 * I_) + bn) * H_ + sc4;
  }

  f32x4 accg[4][2], accu[4][2];
  const f32x4 Z4 = {0.f, 0.f, 0.f, 0.f};
#pragma unroll
  for (int mf = 0; mf < 4; ++mf)
#pragma unroll
    for (int nf = 0; nf < 2; ++nf) { accg[mf][nf] = Z4; accu[mf][nf] = Z4; }

  f32x4 ra[4], rb[4];
#pragma unroll
  for (int q = 0; q < 4; ++q) { ra[q] = *(const f32x4*)(aptr[q]); rb[q] = *(const f32x4*)(bptr[q]); }
#pragma unroll
  for (int q = 0; q < 4; ++q) {
    int r = srow + q * 32; int sc = r * BK + swzc(r, sc4);
    bf16x4 h, l;
    cvt4(ra[q], &h, &l); *(bf16x4*)&lAh[0][sc] = h; *(bf16x4*)&lAl[0][sc] = l;
    cvt4(rb[q], &h, &l); *(bf16x4*)&lBh[0][sc] = h; *(bf16x4*)&lBl[0][sc] = l;
  }
  __syncthreads();

  int arow[4], brow[2];
#pragma unroll
  for (int mf = 0; mf < 4; ++mf) arow[mf] = wm + mf * 16 + lr;
#pragma unroll
  for (int nf = 0; nf < 2; ++nf) brow[nf] = wn + nf * 16 + lr;

  const int NK = H_ / BK;  // 64
  for (int kt = 0; kt < NK; ++kt) {
    const int bs = kt & 1;
    const bool more = (kt + 1 < NK);
    if (more) {
      int k = (kt + 1) * BK;
#pragma unroll
      for (int q = 0; q < 4; ++q) { ra[q] = *(const f32x4*)(aptr[q] + k); rb[q] = *(const f32x4*)(bptr[q] + k); }
    }
    bf16x8 Ah[4], Al[4], Bh[4], Bl[4];  // B: [0..1]=gate, [2..3]=up
#pragma unroll
    for (int mf = 0; mf < 4; ++mf) {
      int rr = arow[mf]; int off = rr * BK + ((lk ^ ((rr >> 1) & 3)) << 3);
      Ah[mf] = *(const bf16x8*)&lAh[bs][off];
      Al[mf] = *(const bf16x8*)&lAl[bs][off];
    }
#pragma unroll
    for (int nf = 0; nf < 2; ++nf) {
      int rg = brow[nf]; int og = rg * BK + ((lk ^ ((rg >> 1) & 3)) << 3);
      Bh[nf] = *(const bf16x8*)&lBh[bs][og];
      Bl[nf] = *(const bf16x8*)&lBl[bs][og];
      int ru = 64 + rg; int ou = ru * BK + ((lk ^ ((ru >> 1) & 3)) << 3);
      Bh[2 + nf] = *(const bf16x8*)&lBh[bs][ou];
      Bl[2 + nf] = *(const bf16x8*)&lBl[bs][ou];
    }
#pragma unroll
    for (int mf = 0; mf < 4; ++mf)
#pragma unroll
      for (int nf = 0; nf < 2; ++nf) {
        accg[mf][nf] = __builtin_amdgcn_mfma_f32_16x16x32_bf16(Ah[mf], Bh[nf], accg[mf][nf], 0, 0, 0);
        accg[mf][nf] = __builtin_amdgcn_mfma_f32_16x16x32_bf16(Ah[mf], Bl[nf], accg[mf][nf], 0, 0, 0);
        accg[mf][nf] = __builtin_amdgcn_mfma_f32_16x16x32_bf16(Al[mf], Bh[nf], accg[mf][nf], 0, 0, 0);
        accu[mf][nf] = __builtin_amdgcn_mfma_f32_16x16x32_bf16(Ah[mf], Bh[2+nf], accu[mf][nf], 0, 0, 0);
        accu[mf][nf] = __builtin_amdgcn_mfma_f32_16x16x32_bf16(Ah[mf], Bl[2+nf], accu[mf][nf], 0, 0, 0);
        accu[mf][nf] = __builtin_amdgcn_mfma_f32_16x16x32_bf16(Al[mf], Bh[2+nf], accu[mf][nf], 0, 0, 0);
      }
    if (more) {
      const int nb = bs ^ 1;
#pragma unroll
      for (int q = 0; q < 4; ++q) {
        int r = srow + q * 32; int sc = r * BK + swzc(r, sc4);
        bf16x4 h, l;
        cvt4(ra[q], &h, &l); *(bf16x4*)&lAh[nb][sc] = h; *(bf16x4*)&lAl[nb][sc] = l;
        cvt4(rb[q], &h, &l); *(bf16x4*)&lBh[nb][sc] = h; *(bf16x4*)&lBl[nb][sc] = l;
      }
    }
    __syncthreads();
  }

  // epilogue: stage U rows + tokens
  if (tS < BM) {
    int i = row0 + tS; if (i >= n) i = n - 1;
    sTok[tS] = tok[e * P_ + i];
  }
  {
    int r2 = tS >> 1, hf = (tS & 1) * 8;
    int i = row0 + r2; if (i >= n) i = n - 1;
    int s = tok[e * P_ + i];
    *(f32x4*)&sU[r2 * R_ + hf]     = *(const f32x4*)&U[(size_t)s * R_ + hf];
    *(f32x4*)&sU[r2 * R_ + hf + 4] = *(const f32x4*)&U[(size_t)s * R_ + hf + 4];
  }
  __syncthreads();

#pragma unroll
  for (int nf = 0; nf < 2; ++nf) {
    int colg = c0 + wn + nf * 16 + lr;
    const float* bg = b1 + ((size_t)e * (2 * I_) + colg) * R_;
    const float* bu = b1 + ((size_t)e * (2 * I_) + I_ + colg) * R_;
    float bgr[R_], bur[R_];
#pragma unroll
    for (int rr = 0; rr < R_; rr += 4) {
      *(f32x4*)&bgr[rr] = *(const f32x4*)(bg + rr);
      *(f32x4*)&bur[rr] = *(const f32x4*)(bu + rr);
    }
#pragma unroll
    for (int mf = 0; mf < 4; ++mf)
#pragma unroll
      for (int j = 0; j < 4; ++j) {
        int trow = wm + mf * 16 + lk * 4 + j;
        float g = accg[mf][nf][j], u = accu[mf][nf][j];
        float ag = 0.f, au = 0.f;
#pragma unroll
        for (int rr = 0; rr < R_; ++rr) { float uv = sU[trow * R_ + rr]; ag += uv * bgr[rr]; au += uv * bur[rr]; }
        g += ag; u += au;
        float a = g / (1.f + __expf(-g)) * u;
        int i = row0 + trow;
        if (i < n) {
          int s = sTok[trow];
          __bf16 hi = (__bf16)a; float hff = (float)hi; __bf16 lo = (__bf16)(a - hff);
          acth[(size_t)s * I_ + colg] = hi;
          actl[(size_t)s * I_ + colg] = lo;
        }
      }
  }
}

// GEMM2: out[t] += w * (act@w2^T + V@b2^T), 128x128 tile, split-bf16 3-pass.
__global__ __launch_bounds__(256, 2) void gemm2_kernel(
    const float* __restrict__ w2, const float* __restrict__ b2,
    const __bf16* __restrict__ acth, const __bf16* __restrict__ actl,
    const float* __restrict__ V, const int* __restrict__ cnt,
    const int* __restrict__ tok, const float* __restrict__ wgt,
    float* __restrict__ out) {
  const int e = blockIdx.z;
  const int n = cnt[e];
  const int row0 = blockIdx.x * BM;
  if (row0 >= n) return;
  const int cb0 = blockIdx.y * 128;

  __shared__ __bf16 lAh[2][BM*BK], lAl[2][BM*BK], lBh[2][BM*BK], lBl[2][BM*BK];
  __shared__ float sV[BM * R_];
  __shared__ float sW[BM];
  __shared__ int sTok[BM];

  const int tS = threadIdx.x;
  const int lane = tS & 63, wid = tS >> 6;
  const int wm = (wid & 1) * 64, wn = (wid >> 1) * 64;
  const int lr = lane & 15, lk = lane >> 4;

  // A staging: bf16 hi/lo direct; row = tS>>1, 16 cols per thread
  const int arow_s = tS >> 1;
  const int acol_s = (tS & 1) * 16;
  const __bf16 *ah_p, *al_p;
  {
    int i = row0 + arow_s; if (i >= n) i = n - 1;
    int s = tok[e * P_ + i];
    ah_p = acth + (size_t)s * I_ + acol_s;
    al_p = actl + (size_t)s * I_ + acol_s;
  }
  // B staging: fp32 convert, like gemm1
  const int srow = tS >> 3;
  const int sc4 = (tS & 7) * 4;
  const float* bptr[4];
#pragma unroll
  for (int q = 0; q < 4; ++q) {
    int r = srow + q * 32;
    bptr[q] = w2 + ((size_t)e * H_ + cb0 + r) * I_ + sc4;
  }

  f32x4 acc[4][4];
  const f32x4 Z4 = {0.f, 0.f, 0.f, 0.f};
#pragma unroll
  for (int mf = 0; mf < 4; ++mf)
#pragma unroll
    for (int nf = 0; nf < 4; ++nf) acc[mf][nf] = Z4;

  bf16x8 rah[2], ral[2]; f32x4 rb[4];
#pragma unroll
  for (int c = 0; c < 2; ++c) { rah[c] = *(const bf16x8*)(ah_p + c * 8); ral[c] = *(const bf16x8*)(al_p + c * 8); }
#pragma unroll
  for (int q = 0; q < 4; ++q) rb[q] = *(const f32x4*)(bptr[q]);
#pragma unroll
  for (int c = 0; c < 2; ++c) {
    int col = acol_s + c * 8;
    int sc = arow_s * BK + swzc(arow_s, col);
    *(bf16x8*)&lAh[0][sc] = rah[c]; *(bf16x8*)&lAl[0][sc] = ral[c];
  }
#pragma unroll
  for (int q = 0; q < 4; ++q) {
    int r = srow + q * 32; int sc = r * BK + swzc(r, sc4);
    bf16x4 h, l; cvt4(rb[q], &h, &l);
    *(bf16x4*)&lBh[0][sc] = h; *(bf16x4*)&lBl[0][sc] = l;
  }
  __syncthreads();

  int arow[4], brow[4];
#pragma unroll
  for (int mf = 0; mf < 4; ++mf) arow[mf] = wm + mf * 16 + lr;
#pragma unroll
  for (int nf = 0; nf < 4; ++nf) brow[nf] = wn + nf * 16 + lr;

  const int NK = I_ / BK;  // 32
  for (int kt = 0; kt < NK; ++kt) {
    const int bs = kt & 1;
    const bool more = (kt + 1 < NK);
    if (more) {
      int k = (kt + 1) * BK;
#pragma unroll
      for (int c = 0; c < 2; ++c) { rah[c] = *(const bf16x8*)(ah_p + k + c * 8); ral[c] = *(const bf16x8*)(al_p + k + c * 8); }
#pragma unroll
      for (int q = 0; q < 4; ++q) rb[q] = *(const f32x4*)(bptr[q] + k);
    }
    bf16x8 Ah[4], Al[4], Bh[4], Bl[4];
#pragma unroll
    for (int mf = 0; mf < 4; ++mf) {
      int rr = arow[mf]; int off = rr * BK + ((lk ^ ((rr >> 1) & 3)) << 3);
      Ah[mf] = *(const bf16x8*)&lAh[bs][off];
      Al[mf] = *(const bf16x8*)&lAl[bs][off];
    }
#pragma unroll
    for (int nf = 0; nf < 4; ++nf) {
      int rr = brow[nf]; int off = rr * BK + ((lk ^ ((rr >> 1) & 3)) << 3);
      Bh[nf] = *(const bf16x8*)&lBh[bs][off];
      Bl[nf] = *(const bf16x8*)&lBl[bs][off];
    }
#pragma unroll
    for (int mf = 0; mf < 4; ++mf)
#pragma unroll
      for (int nf = 0; nf < 4; ++nf) {
        acc[mf][nf] = __builtin_amdgcn_mfma_f32_16x16x32_bf16(Ah[mf], Bh[nf], acc[mf][nf], 0, 0, 0);
        acc[mf][nf] = __builtin_amdgcn_mfma_f32_16x16x32_bf16(Ah[mf], Bl[nf], acc[mf][nf], 0, 0, 0);
        acc[mf][nf] = __builtin_amdgcn_mfma_f32_16x16x32_bf16(Al[mf], Bh[nf], acc[mf][nf], 0, 0, 0);
      }
    if (more) {
      const int nb = bs ^ 1;
#pragma unroll
      for (int c = 0; c < 2; ++c) {
        int col = acol_s + c * 8;
        int sc = arow_s * BK + swzc(arow_s, col);
        *(bf16x8*)&lAh[nb][sc] = rah[c]; *(bf16x8*)&lAl[nb][sc] = ral[c];
      }
#pragma unroll
      for (int q = 0; q < 4; ++q) {
        int r = srow + q * 32; int sc = r * BK + swzc(r, sc4);
        bf16x4 h, l; cvt4(rb[q], &h, &l);
        *(bf16x4*)&lBh[nb][sc] = h; *(bf16x4*)&lBl[nb][sc] = l;
      }
    }
    __syncthreads();
  }

  if (tS < BM) {
    int i = row0 + tS;
    sW[tS] = (i < n) ? wgt[e * P_ + i] : 0.f;
    int ii = (i < n) ? i : (n - 1);
    sTok[tS] = tok[e * P_ + ii];
  }
  {
    int r2 = tS >> 1, hf = (tS & 1) * 8;
    int i = row0 + r2; if (i >= n) i = n - 1;
    int s = tok[e * P_ + i];
    *(f32x4*)&sV[r2 * R_ + hf]     = *(const f32x4*)&V[(size_t)s * R_ + hf];
    *(f32x4*)&sV[r2 * R_ + hf + 4] = *(const f32x4*)&V[(size_t)s * R_ + hf + 4];
  }
  __syncthreads();

#pragma unroll
  for (int nf = 0; nf < 4; ++nf) {
    int col = cb0 + wn + nf * 16 + lr;
    const float* b2p = b2 + ((size_t)e * H_ + col) * R_;
    float br_[R_];
#pragma unroll
    for (int rr = 0; rr < R_; rr += 4) *(f32x4*)&br_[rr] = *(const f32x4*)(b2p + rr);
#pragma unroll
    for (int mf = 0; mf < 4; ++mf)
#pragma unroll
      for (int j = 0; j < 4; ++j) {
        int trow = wm + mf * 16 + lk * 4 + j;
        int i = row0 + trow;
        if (i < n) {
          float y = acc[mf][nf][j];
#pragma unroll
          for (int rr = 0; rr < R_; ++rr) y += sV[trow * R_ + rr] * br_[rr];
          unsafeAtomicAdd(&out[(size_t)(sTok[trow] >> 1) * H_ + col], sW[trow] * y);
        }
      }
  }
}

extern "C" void kernel_launch(void* const* d_in, const int* in_sizes, int n_in,
                              void* d_out, int out_size, void* d_ws, size_t ws_size,
                              hipStream_t stream) {
  const float* x   = (const float*)d_in[0];
  const float* tw  = (const float*)d_in[1];
  const int*   ids = (const int*)d_in[2];
  const float* w13 = (const float*)d_in[3];
  const float* w2  = (const float*)d_in[4];
  const float* a1  = (const float*)d_in[5];
  const float* b1  = (const float*)d_in[6];
  const float* a2  = (const float*)d_in[7];
  const float* b2  = (const float*)d_in[8];
  float* out = (float*)d_out;

  char* ws = (char*)d_ws;
  size_t o = 0;
  int* cnt = (int*)(ws + o);      o += 256;
  int* tok = (int*)(ws + o);      o += (size_t)E_ * P_ * 4;
  float* wgt = (float*)(ws + o);  o += (size_t)E_ * P_ * 4;
  float* U = (float*)(ws + o);    o += (size_t)P_ * R_ * 4;
  float* V = (float*)(ws + o);    o += (size_t)P_ * R_ * 4;
  __bf16* acth = (__bf16*)(ws + o); o += (size_t)P_ * I_ * 2;
  __bf16* actl = (__bf16*)(ws + o); o += (size_t)P_ * I_ * 2;
  if (ws_size < o) return;  // insufficient scratch: fail cleanly (output stays poisoned)

  zero_kernel<<<(T_ * H_ / 4 + 255) / 256, 256, 0, stream>>>(out, cnt);
  route_kernel<<<P_ / 256, 256, 0, stream>>>(ids, tw, cnt, tok, wgt);
  lora_u_kernel<<<P_ / 4, 256, 0, stream>>>(x, a1, ids, U);
  gemm1_kernel<<<dim3(P_ / BM, I_ / 64, E_), 256, 0, stream>>>(x, w13, b1, U, cnt, tok, acth, actl);
  lora_v_kernel<<<P_ / 4, 256, 0, stream>>>(acth, actl, a2, ids, V);
  gemm2_kernel<<<dim3(P_ / BM, H_ / 128, E_), 256, 0, stream>>>(w2, b2, acth, actl, V, cnt, tok, wgt, out);
}

// Round 4
// 2702.531 us; speedup vs baseline: 1.3090x; 1.3090x over previous
//
#include <hip/hip_runtime.h>
#include <hip/hip_bf16.h>

#define T_ 16384
#define H_ 2048
#define I_ 1024
#define E_ 8
#define K_ 2
#define R_ 16
#define P_ (T_*K_)   /* 32768 pairs */
#define BM 128
#define BK 32

typedef float  f32x4  __attribute__((ext_vector_type(4)));
typedef __bf16 bf16x4 __attribute__((ext_vector_type(4)));
typedef __bf16 bf16x8 __attribute__((ext_vector_type(8)));

// XOR swizzle: 8-element (16B) chunk index ^= (row>>1)&3  -> 2-way-free frag reads
__device__ __forceinline__ int swzc(int r, int c) {
  return (c & 7) | ((((c >> 3) ^ ((r >> 1) & 3)) & 3) << 3);
}

// fp32 -> (hi, lo) bf16 split; hi+lo captures ~16 mantissa bits (rel err ~2^-17)
__device__ __forceinline__ void cvt4(f32x4 v, bf16x4* h, bf16x4* l) {
#pragma unroll
  for (int j = 0; j < 4; ++j) {
    float f = v[j];
    __bf16 hh = (__bf16)f;
    (*h)[j] = hh;
    (*l)[j] = (__bf16)(f - (float)hh);
  }
}

__global__ __launch_bounds__(256) void zero_kernel(float* __restrict__ out, int* __restrict__ cnt) {
  size_t i = (size_t)blockIdx.x * 256 + threadIdx.x;
  f32x4 z = {0.f, 0.f, 0.f, 0.f};
  if (i < (size_t)T_ * H_ / 4) ((f32x4*)out)[i] = z;
  if (i < E_) cnt[i] = 0;
}

__global__ __launch_bounds__(256) void route_kernel(const int* __restrict__ ids,
                                                    const float* __restrict__ tw,
                                                    int* __restrict__ cnt,
                                                    int* __restrict__ tok,
                                                    float* __restrict__ wgt) {
  int s = blockIdx.x * 256 + threadIdx.x;
  if (s < P_) {
    int e = ids[s];
    int pos = atomicAdd(&cnt[e], 1);
    tok[e * P_ + pos] = s;
    wgt[e * P_ + pos] = tw[s];
  }
}

// U[s][r] = sum_h x[t][h] * a1[e][r][h]   (one wave per pair)
__global__ __launch_bounds__(256) void lora_u_kernel(const float* __restrict__ x,
                                                     const float* __restrict__ a1,
                                                     const int* __restrict__ ids,
                                                     float* __restrict__ U) {
  int sIdx = blockIdx.x * 4 + (threadIdx.x >> 6);
  int lane = threadIdx.x & 63;
  int t = sIdx >> 1;
  int e = ids[sIdx];
  int r = lane >> 2, part = lane & 3;
  const float* xp = x + (size_t)t * H_;
  const float* ap = a1 + ((size_t)e * R_ + r) * H_;
  float acc = 0.f;
  for (int h0 = part * 4; h0 < H_; h0 += 16) {
    f32x4 xv = *(const f32x4*)(xp + h0);
    f32x4 av = *(const f32x4*)(ap + h0);
    acc += xv[0]*av[0] + xv[1]*av[1] + xv[2]*av[2] + xv[3]*av[3];
  }
  acc += __shfl_xor(acc, 1);
  acc += __shfl_xor(acc, 2);
  if (part == 0) U[(size_t)sIdx * R_ + r] = acc;
}

// V[s][r] = sum_i act[s][i] * a2[e][r][i]
__global__ __launch_bounds__(256) void lora_v_kernel(const __bf16* __restrict__ acth,
                                                     const __bf16* __restrict__ actl,
                                                     const float* __restrict__ a2,
                                                     const int* __restrict__ ids,
                                                     float* __restrict__ V) {
  int sIdx = blockIdx.x * 4 + (threadIdx.x >> 6);
  int lane = threadIdx.x & 63;
  int e = ids[sIdx];
  int r = lane >> 2, part = lane & 3;
  const __bf16* hp = acth + (size_t)sIdx * I_;
  const __bf16* lp = actl + (size_t)sIdx * I_;
  const float* ap = a2 + ((size_t)e * R_ + r) * I_;
  float acc = 0.f;
  for (int i0 = part * 4; i0 < I_; i0 += 16) {
    bf16x4 hv = *(const bf16x4*)(hp + i0);
    bf16x4 lv = *(const bf16x4*)(lp + i0);
    f32x4 av = *(const f32x4*)(ap + i0);
#pragma unroll
    for (int j = 0; j < 4; ++j) acc += ((float)hv[j] + (float)lv[j]) * av[j];
  }
  acc += __shfl_xor(acc, 1);
  acc += __shfl_xor(acc, 2);
  if (part == 0) V[(size_t)sIdx * R_ + r] = acc;
}

// GEMM1: act[s, c] = silu(g)*u, g/u = x@w13^T (+ U@b1^T), split-bf16 3-pass MFMA.
// Block: 128 pair-rows x 64 act cols (gate+up dual accumulators).
// 2-deep register pipeline: loads for kt+2 issued while computing kt; the LDS
// write of kt+1 uses registers loaded a full K-step earlier (vmcnt satisfied).
// Grid: (colblk, rowblk, e) so consecutive blocks share the gathered x row-panel.
__global__ __launch_bounds__(256, 2) void gemm1_kernel(
    const float* __restrict__ x, const float* __restrict__ w13,
    const float* __restrict__ b1, const float* __restrict__ U,
    const int* __restrict__ cnt, const int* __restrict__ tok,
    __bf16* __restrict__ acth, __bf16* __restrict__ actl) {
  const int e = blockIdx.z;
  const int n = cnt[e];
  const int row0 = blockIdx.y * BM;
  if (row0 >= n) return;
  const int c0 = blockIdx.x * 64;

  __shared__ __bf16 lAh[2][BM*BK], lAl[2][BM*BK], lBh[2][BM*BK], lBl[2][BM*BK];
  __shared__ float sU[BM * R_];
  __shared__ int sTok[BM];

  const int tS = threadIdx.x;
  const int lane = tS & 63, wid = tS >> 6;
  const int wm = (wid & 1) * 64, wn = (wid >> 1) * 32;
  const int lr = lane & 15, lk = lane >> 4;

  // staging: thread covers (srow + q*32, sc4..sc4+3), q=0..3, for both A and B tiles
  const int srow = tS >> 3;
  const int sc4 = (tS & 7) * 4;
  const float* aptr[4];
  const float* bptr[4];
#pragma unroll
  for (int q = 0; q < 4; ++q) {
    int r = srow + q * 32;
    int i = row0 + r; if (i >= n) i = n - 1;
    int s = tok[e * P_ + i];
    aptr[q] = x + (size_t)(s >> 1) * H_ + sc4;
    int bn = (r < 64) ? (c0 + r) : (I_ + c0 + (r - 64));
    bptr[q] = w13 + ((size_t)e * (2 * I_) + bn) * H_ + sc4;
  }

  f32x4 accg[4][2], accu[4][2];
  const f32x4 Z4 = {0.f, 0.f, 0.f, 0.f};
#pragma unroll
  for (int mf = 0; mf < 4; ++mf)
#pragma unroll
    for (int nf = 0; nf < 2; ++nf) { accg[mf][nf] = Z4; accu[mf][nf] = Z4; }

  int arow[4], brow[2];
#pragma unroll
  for (int mf = 0; mf < 4; ++mf) arow[mf] = wm + mf * 16 + lr;
#pragma unroll
  for (int nf = 0; nf < 2; ++nf) brow[nf] = wn + nf * 16 + lr;

  f32x4 ra0[4], rb0[4], ra1[4], rb1[4];

  auto g1_load = [&](f32x4* rA, f32x4* rB, int kof) {
#pragma unroll
    for (int q = 0; q < 4; ++q) {
      rA[q] = *(const f32x4*)(aptr[q] + kof);
      rB[q] = *(const f32x4*)(bptr[q] + kof);
    }
  };
  auto g1_write = [&](int buf, const f32x4* rA, const f32x4* rB) {
#pragma unroll
    for (int q = 0; q < 4; ++q) {
      int r = srow + q * 32; int sc = r * BK + swzc(r, sc4);
      bf16x4 h, l;
      cvt4(rA[q], &h, &l); *(bf16x4*)&lAh[buf][sc] = h; *(bf16x4*)&lAl[buf][sc] = l;
      cvt4(rB[q], &h, &l); *(bf16x4*)&lBh[buf][sc] = h; *(bf16x4*)&lBl[buf][sc] = l;
    }
  };
  auto g1_step = [&](int bs) {
    bf16x8 Ah[4], Al[4], Bh[4], Bl[4];  // B: [0..1]=gate, [2..3]=up
#pragma unroll
    for (int mf = 0; mf < 4; ++mf) {
      int rr = arow[mf]; int off = rr * BK + ((lk ^ ((rr >> 1) & 3)) << 3);
      Ah[mf] = *(const bf16x8*)&lAh[bs][off];
      Al[mf] = *(const bf16x8*)&lAl[bs][off];
    }
#pragma unroll
    for (int nf = 0; nf < 2; ++nf) {
      int rg = brow[nf]; int og = rg * BK + ((lk ^ ((rg >> 1) & 3)) << 3);
      Bh[nf] = *(const bf16x8*)&lBh[bs][og];
      Bl[nf] = *(const bf16x8*)&lBl[bs][og];
      int ru = 64 + rg; int ou = ru * BK + ((lk ^ ((ru >> 1) & 3)) << 3);
      Bh[2 + nf] = *(const bf16x8*)&lBh[bs][ou];
      Bl[2 + nf] = *(const bf16x8*)&lBl[bs][ou];
    }
#pragma unroll
    for (int mf = 0; mf < 4; ++mf)
#pragma unroll
      for (int nf = 0; nf < 2; ++nf) {
        accg[mf][nf] = __builtin_amdgcn_mfma_f32_16x16x32_bf16(Ah[mf], Bh[nf], accg[mf][nf], 0, 0, 0);
        accg[mf][nf] = __builtin_amdgcn_mfma_f32_16x16x32_bf16(Ah[mf], Bl[nf], accg[mf][nf], 0, 0, 0);
        accg[mf][nf] = __builtin_amdgcn_mfma_f32_16x16x32_bf16(Al[mf], Bh[nf], accg[mf][nf], 0, 0, 0);
        accu[mf][nf] = __builtin_amdgcn_mfma_f32_16x16x32_bf16(Ah[mf], Bh[2+nf], accu[mf][nf], 0, 0, 0);
        accu[mf][nf] = __builtin_amdgcn_mfma_f32_16x16x32_bf16(Ah[mf], Bl[2+nf], accu[mf][nf], 0, 0, 0);
        accu[mf][nf] = __builtin_amdgcn_mfma_f32_16x16x32_bf16(Al[mf], Bh[2+nf], accu[mf][nf], 0, 0, 0);
      }
  };

  const int NK = H_ / BK;  // 64 (even)
  // prologue: kt=0 -> lds[0]; kt=1 -> regs
  g1_load(ra0, rb0, 0);
  g1_write(0, ra0, rb0);
  g1_load(ra1, rb1, BK);
  __syncthreads();

  for (int kt = 0; kt < NK; kt += 2) {
    // even: compute lds[0] (kt); write kt+1 -> lds[1]; prefetch kt+2 -> set0
    if (kt + 2 < NK) g1_load(ra0, rb0, (kt + 2) * BK);
    g1_step(0);
    g1_write(1, ra1, rb1);
    __syncthreads();
    // odd: compute lds[1] (kt+1); write kt+2 -> lds[0]; prefetch kt+3 -> set1
    if (kt + 3 < NK) g1_load(ra1, rb1, (kt + 3) * BK);
    g1_step(1);
    if (kt + 2 < NK) g1_write(0, ra0, rb0);
    __syncthreads();
  }

  // epilogue: stage U rows + tokens
  if (tS < BM) {
    int i = row0 + tS; if (i >= n) i = n - 1;
    sTok[tS] = tok[e * P_ + i];
  }
  {
    int r2 = tS >> 1, hf = (tS & 1) * 8;
    int i = row0 + r2; if (i >= n) i = n - 1;
    int s = tok[e * P_ + i];
    *(f32x4*)&sU[r2 * R_ + hf]     = *(const f32x4*)&U[(size_t)s * R_ + hf];
    *(f32x4*)&sU[r2 * R_ + hf + 4] = *(const f32x4*)&U[(size_t)s * R_ + hf + 4];
  }
  __syncthreads();

#pragma unroll
  for (int nf = 0; nf < 2; ++nf) {
    int colg = c0 + wn + nf * 16 + lr;
    const float* bg = b1 + ((size_t)e * (2 * I_) + colg) * R_;
    const float* bu = b1 + ((size_t)e * (2 * I_) + I_ + colg) * R_;
    float bgr[R_], bur[R_];
#pragma unroll
    for (int rr = 0; rr < R_; rr += 4) {
      *(f32x4*)&bgr[rr] = *(const f32x4*)(bg + rr);
      *(f32x4*)&bur[rr] = *(const f32x4*)(bu + rr);
    }
#pragma unroll
    for (int mf = 0; mf < 4; ++mf)
#pragma unroll
      for (int j = 0; j < 4; ++j) {
        int trow = wm + mf * 16 + lk * 4 + j;
        float g = accg[mf][nf][j], u = accu[mf][nf][j];
        float ag = 0.f, au = 0.f;
#pragma unroll
        for (int rr = 0; rr < R_; ++rr) { float uv = sU[trow * R_ + rr]; ag += uv * bgr[rr]; au += uv * bur[rr]; }
        g += ag; u += au;
        float a = g / (1.f + __expf(-g)) * u;
        int i = row0 + trow;
        if (i < n) {
          int s = sTok[trow];
          __bf16 hi = (__bf16)a; float hff = (float)hi; __bf16 lo = (__bf16)(a - hff);
          acth[(size_t)s * I_ + colg] = hi;
          actl[(size_t)s * I_ + colg] = lo;
        }
      }
  }
}

// GEMM2: out[t] += w * (act@w2^T + V@b2^T), 128x128 tile, split-bf16 3-pass,
// same 2-deep register pipeline. Grid: (colblk, rowblk, e).
__global__ __launch_bounds__(256, 2) void gemm2_kernel(
    const float* __restrict__ w2, const float* __restrict__ b2,
    const __bf16* __restrict__ acth, const __bf16* __restrict__ actl,
    const float* __restrict__ V, const int* __restrict__ cnt,
    const int* __restrict__ tok, const float* __restrict__ wgt,
    float* __restrict__ out) {
  const int e = blockIdx.z;
  const int n = cnt[e];
  const int row0 = blockIdx.y * BM;
  if (row0 >= n) return;
  const int cb0 = blockIdx.x * 128;

  __shared__ __bf16 lAh[2][BM*BK], lAl[2][BM*BK], lBh[2][BM*BK], lBl[2][BM*BK];
  __shared__ float sV[BM * R_];
  __shared__ float sW[BM];
  __shared__ int sTok[BM];

  const int tS = threadIdx.x;
  const int lane = tS & 63, wid = tS >> 6;
  const int wm = (wid & 1) * 64, wn = (wid >> 1) * 64;
  const int lr = lane & 15, lk = lane >> 4;

  // A staging: bf16 hi/lo direct; row = tS>>1, 16 cols per thread
  const int arow_s = tS >> 1;
  const int acol_s = (tS & 1) * 16;
  const __bf16 *ah_p, *al_p;
  {
    int i = row0 + arow_s; if (i >= n) i = n - 1;
    int s = tok[e * P_ + i];
    ah_p = acth + (size_t)s * I_ + acol_s;
    al_p = actl + (size_t)s * I_ + acol_s;
  }
  // B staging: fp32 convert, like gemm1
  const int srow = tS >> 3;
  const int sc4 = (tS & 7) * 4;
  const float* bptr[4];
#pragma unroll
  for (int q = 0; q < 4; ++q) {
    int r = srow + q * 32;
    bptr[q] = w2 + ((size_t)e * H_ + cb0 + r) * I_ + sc4;
  }

  f32x4 acc[4][4];
  const f32x4 Z4 = {0.f, 0.f, 0.f, 0.f};
#pragma unroll
  for (int mf = 0; mf < 4; ++mf)
#pragma unroll
    for (int nf = 0; nf < 4; ++nf) acc[mf][nf] = Z4;

  int arow[4], brow[4];
#pragma unroll
  for (int mf = 0; mf < 4; ++mf) arow[mf] = wm + mf * 16 + lr;
#pragma unroll
  for (int nf = 0; nf < 4; ++nf) brow[nf] = wn + nf * 16 + lr;

  bf16x8 rah0[2], ral0[2], rah1[2], ral1[2];
  f32x4 rb0[4], rb1[4];

  auto g2_load = [&](bf16x8* rh, bf16x8* rl, f32x4* rB, int kof) {
#pragma unroll
    for (int c = 0; c < 2; ++c) {
      rh[c] = *(const bf16x8*)(ah_p + kof + c * 8);
      rl[c] = *(const bf16x8*)(al_p + kof + c * 8);
    }
#pragma unroll
    for (int q = 0; q < 4; ++q) rB[q] = *(const f32x4*)(bptr[q] + kof);
  };
  auto g2_write = [&](int buf, const bf16x8* rh, const bf16x8* rl, const f32x4* rB) {
#pragma unroll
    for (int c = 0; c < 2; ++c) {
      int col = acol_s + c * 8;
      int sc = arow_s * BK + swzc(arow_s, col);
      *(bf16x8*)&lAh[buf][sc] = rh[c]; *(bf16x8*)&lAl[buf][sc] = rl[c];
    }
#pragma unroll
    for (int q = 0; q < 4; ++q) {
      int r = srow + q * 32; int sc = r * BK + swzc(r, sc4);
      bf16x4 h, l; cvt4(rB[q], &h, &l);
      *(bf16x4*)&lBh[buf][sc] = h; *(bf16x4*)&lBl[buf][sc] = l;
    }
  };
  auto g2_step = [&](int bs) {
    bf16x8 Ah[4], Al[4];
#pragma unroll
    for (int mf = 0; mf < 4; ++mf) {
      int rr = arow[mf]; int off = rr * BK + ((lk ^ ((rr >> 1) & 3)) << 3);
      Ah[mf] = *(const bf16x8*)&lAh[bs][off];
      Al[mf] = *(const bf16x8*)&lAl[bs][off];
    }
#pragma unroll
    for (int nf = 0; nf < 4; ++nf) {
      int rr = brow[nf]; int off = rr * BK + ((lk ^ ((rr >> 1) & 3)) << 3);
      bf16x8 Bh = *(const bf16x8*)&lBh[bs][off];
      bf16x8 Bl = *(const bf16x8*)&lBl[bs][off];
#pragma unroll
      for (int mf = 0; mf < 4; ++mf) {
        acc[mf][nf] = __builtin_amdgcn_mfma_f32_16x16x32_bf16(Ah[mf], Bh, acc[mf][nf], 0, 0, 0);
        acc[mf][nf] = __builtin_amdgcn_mfma_f32_16x16x32_bf16(Ah[mf], Bl, acc[mf][nf], 0, 0, 0);
        acc[mf][nf] = __builtin_amdgcn_mfma_f32_16x16x32_bf16(Al[mf], Bh, acc[mf][nf], 0, 0, 0);
      }
    }
  };

  const int NK = I_ / BK;  // 32 (even)
  g2_load(rah0, ral0, rb0, 0);
  g2_write(0, rah0, ral0, rb0);
  g2_load(rah1, ral1, rb1, BK);
  __syncthreads();

  for (int kt = 0; kt < NK; kt += 2) {
    if (kt + 2 < NK) g2_load(rah0, ral0, rb0, (kt + 2) * BK);
    g2_step(0);
    g2_write(1, rah1, ral1, rb1);
    __syncthreads();
    if (kt + 3 < NK) g2_load(rah1, ral1, rb1, (kt + 3) * BK);
    g2_step(1);
    if (kt + 2 < NK) g2_write(0, rah0, ral0, rb0);
    __syncthreads();
  }

  if (tS < BM) {
    int i = row0 + tS;
    sW[tS] = (i < n) ? wgt[e * P_ + i] : 0.f;
    int ii = (i < n) ? i : (n - 1);
    sTok[tS] = tok[e * P_ + ii];
  }
  {
    int r2 = tS >> 1, hf = (tS & 1) * 8;
    int i = row0 + r2; if (i >= n) i = n - 1;
    int s = tok[e * P_ + i];
    *(f32x4*)&sV[r2 * R_ + hf]     = *(const f32x4*)&V[(size_t)s * R_ + hf];
    *(f32x4*)&sV[r2 * R_ + hf + 4] = *(const f32x4*)&V[(size_t)s * R_ + hf + 4];
  }
  __syncthreads();

#pragma unroll
  for (int nf = 0; nf < 4; ++nf) {
    int col = cb0 + wn + nf * 16 + lr;
    const float* b2p = b2 + ((size_t)e * H_ + col) * R_;
    float br_[R_];
#pragma unroll
    for (int rr = 0; rr < R_; rr += 4) *(f32x4*)&br_[rr] = *(const f32x4*)(b2p + rr);
#pragma unroll
    for (int mf = 0; mf < 4; ++mf)
#pragma unroll
      for (int j = 0; j < 4; ++j) {
        int trow = wm + mf * 16 + lk * 4 + j;
        int i = row0 + trow;
        if (i < n) {
          float y = acc[mf][nf][j];
#pragma unroll
          for (int rr = 0; rr < R_; ++rr) y += sV[trow * R_ + rr] * br_[rr];
          unsafeAtomicAdd(&out[(size_t)(sTok[trow] >> 1) * H_ + col], sW[trow] * y);
        }
      }
  }
}

extern "C" void kernel_launch(void* const* d_in, const int* in_sizes, int n_in,
                              void* d_out, int out_size, void* d_ws, size_t ws_size,
                              hipStream_t stream) {
  const float* x   = (const float*)d_in[0];
  const float* tw  = (const float*)d_in[1];
  const int*   ids = (const int*)d_in[2];
  const float* w13 = (const float*)d_in[3];
  const float* w2  = (const float*)d_in[4];
  const float* a1  = (const float*)d_in[5];
  const float* b1  = (const float*)d_in[6];
  const float* a2  = (const float*)d_in[7];
  const float* b2  = (const float*)d_in[8];
  float* out = (float*)d_out;

  char* ws = (char*)d_ws;
  size_t o = 0;
  int* cnt = (int*)(ws + o);      o += 256;
  int* tok = (int*)(ws + o);      o += (size_t)E_ * P_ * 4;
  float* wgt = (float*)(ws + o);  o += (size_t)E_ * P_ * 4;
  float* U = (float*)(ws + o);    o += (size_t)P_ * R_ * 4;
  float* V = (float*)(ws + o);    o += (size_t)P_ * R_ * 4;
  __bf16* acth = (__bf16*)(ws + o); o += (size_t)P_ * I_ * 2;
  __bf16* actl = (__bf16*)(ws + o); o += (size_t)P_ * I_ * 2;
  if (ws_size < o) return;  // insufficient scratch: fail cleanly (output stays poisoned)

  zero_kernel<<<(T_ * H_ / 4 + 255) / 256, 256, 0, stream>>>(out, cnt);
  route_kernel<<<P_ / 256, 256, 0, stream>>>(ids, tw, cnt, tok, wgt);
  lora_u_kernel<<<P_ / 4, 256, 0, stream>>>(x, a1, ids, U);
  gemm1_kernel<<<dim3(I_ / 64, P_ / BM, E_), 256, 0, stream>>>(x, w13, b1, U, cnt, tok, acth, actl);
  lora_v_kernel<<<P_ / 4, 256, 0, stream>>>(acth, actl, a2, ids, V);
  gemm2_kernel<<<dim3(H_ / 128, P_ / BM, E_), 256, 0, stream>>>(w2, b2, acth, actl, V, cnt, tok, wgt, out);
}